// Round 29
// baseline (443.812 us; speedup 1.0000x reference)
//
#include <hip/hip_runtime.h>

#define IND 256
#define KC  32

// ============ Kernel A: champion (R25, 42.9 us) — unchanged ============
__global__ __launch_bounds__(256, 4)
void FeatureEncodingLayer_30374008718005_kernel(
        const float* __restrict__ X,      // [1024][256]
        const float* __restrict__ W,      // [4096][256]
        const float* __restrict__ bias,   // [4096]
        float* __restrict__ outf)         // [1024][4][4][2048] float32 = Re(kron)
{
    __shared__ float Ws[2][KC / 2][256];   // 32 KB

    const int tid  = threadIdx.x;
    const int lane = tid & 63;
    const int wid  = __builtin_amdgcn_readfirstlane(tid >> 6);

    const int bid = ((int)blockIdx.x & 7) * 128 + ((int)blockIdx.x >> 3);
    const int ut = bid & 31;
    const int bt = bid >> 5;
    const int b0 = bt * 32;
    const int u0 = ut * 128;
    const int p0 = ut * 64;

    const int q  = tid & 7;
    const int rq = tid >> 3;

    const float* xc = X + (size_t)(b0 + 8 * wid) * IND;

    float acc[8][2];
#pragma unroll
    for (int i = 0; i < 8; ++i) { acc[i][0] = 0.f; acc[i][1] = 0.f; }

    float4 pf[4];
#define STAGE_LOAD(c) do {                                                     \
    _Pragma("unroll")                                                          \
    for (int j = 0; j < 4; ++j)                                                \
        pf[j] = *reinterpret_cast<const float4*>(                              \
            W + (size_t)(u0 + rq + 32 * j) * IND + (c) * KC + q * 4);          \
    } while (0)

#define STAGE_WRITE(buf) do {                                                  \
    const int kp0 = 2 * q, kp1 = 2 * q + 1;                                    \
    const int sw0 = (kp0 & 7) << 2, sw1 = (kp1 & 7) << 2;                      \
    _Pragma("unroll")                                                          \
    for (int j = 0; j < 4; ++j) {                                              \
        const int u2 = 2 * (rq + 32 * j);                                      \
        *reinterpret_cast<float2*>(&Ws[buf][kp0][u2 ^ sw0]) =                  \
            make_float2(pf[j].x, pf[j].y);                                     \
        *reinterpret_cast<float2*>(&Ws[buf][kp1][u2 ^ sw1]) =                  \
            make_float2(pf[j].z, pf[j].w);                                     \
    }                                                                          \
    } while (0)

#define LDS_BARRIER() do {                                                     \
    asm volatile("s_waitcnt lgkmcnt(0)" ::: "memory");                         \
    __builtin_amdgcn_s_barrier();                                              \
    } while (0)

    STAGE_LOAD(0);
    STAGE_WRITE(0);
    LDS_BARRIER();

    for (int c = 0; c < IND / KC; ++c) {
        const int cur = c & 1;
        if (c < IND / KC - 1) STAGE_LOAD(c + 1);

        {
            const int zrc = (int)((0xEDB87421u >> (4 * c)) & 0xFu);
            float* zp = outf + (size_t)(b0 + 8 * wid) * 32768
                       + (size_t)zrc * 2048 + p0 + lane;
#pragma unroll
            for (int i = 0; i < 8; ++i)
                __builtin_nontemporal_store(0.f, zp + (size_t)i * 32768);
        }

#pragma unroll
        for (int kp = 0; kp < KC / 2; ++kp) {
            const int sw = (kp & 7) << 2;
            const float4 wq = *reinterpret_cast<const float4*>(
                &Ws[cur][kp][(4 * lane) ^ sw]);
            const int kg = c * KC + 2 * kp;
#pragma unroll
            for (int i = 0; i < 8; ++i) {
                const float x0 = xc[i * IND + kg];
                const float x1 = xc[i * IND + kg + 1];
                acc[i][0] = fmaf(x0, wq.x, acc[i][0]);
                acc[i][0] = fmaf(x1, wq.y, acc[i][0]);
                acc[i][1] = fmaf(x0, wq.z, acc[i][1]);
                acc[i][1] = fmaf(x1, wq.w, acc[i][1]);
            }
        }
        if (c < IND / KC - 1) {
            STAGE_WRITE(cur ^ 1);
            LDS_BARRIER();
        }
    }
#undef STAGE_LOAD
#undef STAGE_WRITE
#undef LDS_BARRIER

    const float2 bv = *reinterpret_cast<const float2*>(bias + u0 + 2 * lane);

#pragma unroll
    for (int i = 0; i < 8; ++i) {
        const int b = b0 + 8 * wid + i;
        const float tA = acc[i][0] + bv.x;
        const float tB = acc[i][1] + bv.y;
        float sA, cA, sB, cB;
        __sincosf(tA, &sA, &cA);
        __sincosf(tB, &sB, &cB);
        const float ca = 0.5f * (1.f + cA);
        const float sa = 0.5f * (1.f - cA);
        const float cb = 0.5f * (1.f + cB);
        const float sb = 0.5f * (1.f - cB);
        const float oo = 0.25f * sA * sB;

        float* bp = outf + (size_t)b * 32768 + p0 + lane;
        __builtin_nontemporal_store( ca * cb, bp +  0 * 2048);
        __builtin_nontemporal_store(-oo,      bp +  3 * 2048);
        __builtin_nontemporal_store( ca * sb, bp +  5 * 2048);
        __builtin_nontemporal_store( oo,      bp +  6 * 2048);
        __builtin_nontemporal_store( oo,      bp +  9 * 2048);
        __builtin_nontemporal_store( sa * cb, bp + 10 * 2048);
        __builtin_nontemporal_store(-oo,      bp + 12 * 2048);
        __builtin_nontemporal_store( sa * sb, bp + 15 * 2048);
    }
}

// ===== Kernel C: store-pattern probe, x6 repeats (runs BEFORE A; A overwrites) =====
__global__ __launch_bounds__(256, 4)
void FE_probe_store6(float* __restrict__ outf, float zval)   // zval = 0.0f (opaque)
{
    const int tid  = threadIdx.x;
    const int lane = tid & 63;
    const int wid  = tid >> 6;
    const int bid = ((int)blockIdx.x & 7) * 128 + ((int)blockIdx.x >> 3);
    const int ut = bid & 31;
    const int bt = bid >> 5;
    const int b0 = bt * 32;
    const int p0 = ut * 64;

#pragma unroll 1
    for (int r = 0; r < 6; ++r) {
        const float v = fmaf((float)r, zval, zval);   // == 0, not const-foldable
        // in-loop zero-slot pattern (8 chunks x one rc x 8 batches)
#pragma unroll 1
        for (int c = 0; c < 8; ++c) {
            const int zrc = (int)((0xEDB87421u >> (4 * c)) & 0xFu);
            float* zp = outf + (size_t)(b0 + 8 * wid) * 32768
                       + (size_t)zrc * 2048 + p0 + lane;
#pragma unroll
            for (int i = 0; i < 8; ++i)
                __builtin_nontemporal_store(v, zp + (size_t)i * 32768);
        }
        // epilogue nonzero-slot pattern (8 batches x 8 slots)
#pragma unroll 1
        for (int i = 0; i < 8; ++i) {
            float* bp = outf + (size_t)(b0 + 8 * wid + i) * 32768 + p0 + lane;
            __builtin_nontemporal_store(v, bp +  0 * 2048);
            __builtin_nontemporal_store(v, bp +  3 * 2048);
            __builtin_nontemporal_store(v, bp +  5 * 2048);
            __builtin_nontemporal_store(v, bp +  6 * 2048);
            __builtin_nontemporal_store(v, bp +  9 * 2048);
            __builtin_nontemporal_store(v, bp + 10 * 2048);
            __builtin_nontemporal_store(v, bp + 12 * 2048);
            __builtin_nontemporal_store(v, bp + 15 * 2048);
        }
    }
}

// ===== Kernel B: compute-only probe, x4 repeats (no global stores; asm sinks) =====
__global__ __launch_bounds__(256, 4)
void FE_probe_compute4(const float* __restrict__ X, const float* __restrict__ W,
                       const float* __restrict__ bias)
{
    __shared__ float Ws[2][KC / 2][256];

    const int tid  = threadIdx.x;
    const int lane = tid & 63;
    const int wid  = __builtin_amdgcn_readfirstlane(tid >> 6);
    const int bid = ((int)blockIdx.x & 7) * 128 + ((int)blockIdx.x >> 3);
    const int ut = bid & 31;
    const int bt = bid >> 5;
    const int b0 = bt * 32;
    const int u0 = ut * 128;

    const int q  = tid & 7;
    const int rq = tid >> 3;
    const float* xc = X + (size_t)(b0 + 8 * wid) * IND;

    float4 pf[4];
#define STAGE_LOAD(c) do {                                                     \
    _Pragma("unroll")                                                          \
    for (int j = 0; j < 4; ++j)                                                \
        pf[j] = *reinterpret_cast<const float4*>(                              \
            W + (size_t)(u0 + rq + 32 * j) * IND + (c) * KC + q * 4);          \
    } while (0)
#define STAGE_WRITE(buf) do {                                                  \
    const int kp0 = 2 * q, kp1 = 2 * q + 1;                                    \
    const int sw0 = (kp0 & 7) << 2, sw1 = (kp1 & 7) << 2;                      \
    _Pragma("unroll")                                                          \
    for (int j = 0; j < 4; ++j) {                                              \
        const int u2 = 2 * (rq + 32 * j);                                      \
        *reinterpret_cast<float2*>(&Ws[buf][kp0][u2 ^ sw0]) =                  \
            make_float2(pf[j].x, pf[j].y);                                     \
        *reinterpret_cast<float2*>(&Ws[buf][kp1][u2 ^ sw1]) =                  \
            make_float2(pf[j].z, pf[j].w);                                     \
    }                                                                          \
    } while (0)
#define LDS_BARRIER() do {                                                     \
    asm volatile("s_waitcnt lgkmcnt(0)" ::: "memory");                         \
    __builtin_amdgcn_s_barrier();                                              \
    } while (0)

#pragma unroll 1
    for (int r = 0; r < 4; ++r) {
        float acc[8][2];
#pragma unroll
        for (int i = 0; i < 8; ++i) { acc[i][0] = 0.f; acc[i][1] = 0.f; }

        STAGE_LOAD(0);
        STAGE_WRITE(0);
        LDS_BARRIER();

#pragma unroll 1
        for (int c = 0; c < IND / KC; ++c) {
            const int cur = c & 1;
            if (c < IND / KC - 1) STAGE_LOAD(c + 1);
#pragma unroll
            for (int kp = 0; kp < KC / 2; ++kp) {
                const int sw = (kp & 7) << 2;
                const float4 wq = *reinterpret_cast<const float4*>(
                    &Ws[cur][kp][(4 * lane) ^ sw]);
                const int kg = c * KC + 2 * kp;
#pragma unroll
                for (int i = 0; i < 8; ++i) {
                    const float x0 = xc[i * IND + kg];
                    const float x1 = xc[i * IND + kg + 1];
                    acc[i][0] = fmaf(x0, wq.x, acc[i][0]);
                    acc[i][0] = fmaf(x1, wq.y, acc[i][0]);
                    acc[i][1] = fmaf(x0, wq.z, acc[i][1]);
                    acc[i][1] = fmaf(x1, wq.w, acc[i][1]);
                }
            }
            if (c < IND / KC - 1) {
                STAGE_WRITE(cur ^ 1);
                LDS_BARRIER();
            }
        }
        LDS_BARRIER();   // make dbuf reuse safe across repeats

        const float2 bv = *reinterpret_cast<const float2*>(bias + u0 + 2 * lane);
#pragma unroll
        for (int i = 0; i < 8; ++i) {
            const float tA = acc[i][0] + bv.x;
            const float tB = acc[i][1] + bv.y;
            float sA, cA, sB, cB;
            __sincosf(tA, &sA, &cA);
            __sincosf(tB, &sB, &cB);
            const float ca = 0.5f * (1.f + cA);
            const float sa = 0.5f * (1.f - cA);
            const float cb = 0.5f * (1.f + cB);
            const float sb = 0.5f * (1.f - cB);
            const float oo = 0.25f * sA * sB;
            asm volatile("" :: "v"(ca), "v"(sa), "v"(cb), "v"(sb), "v"(oo));
        }
    }
#undef STAGE_LOAD
#undef STAGE_WRITE
#undef LDS_BARRIER
}

extern "C" void kernel_launch(void* const* d_in, const int* in_sizes, int n_in,
                              void* d_out, int out_size, void* d_ws, size_t ws_size,
                              hipStream_t stream) {
    const float* X  = (const float*)d_in[0];
    const float* W  = (const float*)d_in[1];
    const float* bv = (const float*)d_in[2];
    float* out = (float*)d_out;

    // DIAGNOSTIC ROUND: C (store-pattern x6, zeros -- overwritten by A),
    // then A (real output), then B (compute-only x4, no stores).
    // Per-dispatch durations surface in the rocprof top-5 table.
    FE_probe_store6<<<dim3(1024), dim3(256), 0, stream>>>(out, 0.0f);
    FeatureEncodingLayer_30374008718005_kernel<<<dim3(1024), dim3(256), 0, stream>>>(
        X, W, bv, out);
    FE_probe_compute4<<<dim3(1024), dim3(256), 0, stream>>>(X, W, bv);
}